// Round 1
// baseline (788.354 us; speedup 1.0000x reference)
//
#include <hip/hip_runtime.h>

#define B_SZ 512
#define E_SZ 512
#define C_SZ 70722
#define NPAD 70784   /* 553*128 */
#define NTILES 553
#define EPSC 0.001f
#define MMARG 0.4f
#define HC 0.333f
#define SC 64.0f
#define PI_F 3.14159265358979323846f

typedef __attribute__((ext_vector_type(8))) short short8;
typedef __attribute__((ext_vector_type(4))) float f32x4;

__device__ __forceinline__ unsigned short f32_to_bf16(float f) {
  unsigned int u = __builtin_bit_cast(unsigned int, f);
  u += 0x7fffu + ((u >> 16) & 1u);   // RNE (inputs finite)
  return (unsigned short)(u >> 16);
}

__device__ __forceinline__ void load16(void* lds, const void* g) {
  __builtin_amdgcn_global_load_lds(
      (const __attribute__((address_space(1))) void*)g,
      (__attribute__((address_space(3))) void*)lds, 16, 0, 0);
}

// ---------------- stats: per-row scalars (1 block, 512 threads) -------------
__global__ __launch_bounds__(512) void k_stats(
    const float* __restrict__ norms, const int* __restrict__ label,
    float* __restrict__ g_ang, float* __restrict__ g_add,
    float* __restrict__ out_cw) {
  __shared__ float sn[512];
  __shared__ int   lab[512];
  __shared__ float red[512];
  const int t = threadIdx.x;
  float x = norms[t];
  x = fminf(fmaxf(x, 0.001f), 100.0f);   // safe_norms
  sn[t] = x; lab[t] = label[t]; red[t] = x;
  __syncthreads();
  for (int s = 256; s > 0; s >>= 1) { if (t < s) red[t] += red[t + s]; __syncthreads(); }
  const float mean = red[0] * (1.0f / 512.0f);
  __syncthreads();
  const float d = x - mean;
  red[t] = d * d;
  __syncthreads();
  for (int s = 256; s > 0; s >>= 1) { if (t < s) red[t] += red[t + s]; __syncthreads(); }
  const float stdv = sqrtf(red[0] / 511.0f);     // ddof=1; T_ALPHA=1
  const float denom = stdv + EPSC;
  float cnt = 0.f, sum = 0.f;
  const int myl = lab[t];
  for (int j = 0; j < 512; ++j) { if (lab[j] == myl) { cnt += 1.0f; sum += sn[j]; } }
  const float cwm = sum / cnt;
  const float ms = fminf(fmaxf((x - mean) / denom * HC, -1.0f), 1.0f);
  out_cw[t] = fminf(fmaxf((x - cwm) / denom, -1.0f), 1.0f) * HC;
  g_ang[t] = -MMARG * ms;
  g_add[t] = MMARG + MMARG * ms;
}

// ---------------- emb f32 -> bf16 (vectorized: 8 elems/thread) --------------
__global__ __launch_bounds__(256) void k_convert_emb(
    const float* __restrict__ emb, unsigned short* __restrict__ Abf) {
  const int i = (blockIdx.x * 256 + threadIdx.x) * 8;
  const f32x4 a = *(const f32x4*)(emb + i);
  const f32x4 b = *(const f32x4*)(emb + i + 4);
  short8 o;
  o[0] = (short)f32_to_bf16(a[0]); o[1] = (short)f32_to_bf16(a[1]);
  o[2] = (short)f32_to_bf16(a[2]); o[3] = (short)f32_to_bf16(a[3]);
  o[4] = (short)f32_to_bf16(b[0]); o[5] = (short)f32_to_bf16(b[1]);
  o[6] = (short)f32_to_bf16(b[2]); o[7] = (short)f32_to_bf16(b[3]);
  *(short8*)(Abf + i) = o;
}

// ------- transpose+convert kernel[:,0,:] -> Bt[c][e] bf16, + invnorm --------
// v2: float4 global loads (16B/lane), vector LDS writes (conflict-free),
//     conflict-free read-transpose, short8 (16B) global stores.
__global__ __launch_bounds__(256) void k_prep_b(
    const float* __restrict__ Kr, unsigned short* __restrict__ Bt,
    float* __restrict__ invn) {
  __shared__ __align__(16) float Tr[64][68];   // [e][c], stride 68 keeps 16B-aligned vec writes
  __shared__ float part[64][8];
  const int t  = threadIdx.x;
  const int c0 = blockIdx.x * 64;
  const int lr = t >> 4;        // load phase: e-row base 0..15
  const int lq = t & 15;        // load phase: float4 column index
  const int rc = t & 31;        // read phase: c base (c = rc, rc+32)
  const int ro = t >> 5;        // read phase: e-octet 0..7
  float accv[2] = {0.f, 0.f};

  for (int et = 0; et < 8; ++et) {
    const int e0 = et * 64;
    // load 64e x 64c f32 tile; per quarter-wave: 16 float4 = 256B contiguous
#pragma unroll
    for (int i = 0; i < 4; ++i) {
      const int rr = lr + 16 * i;
      const f32x4 v = *(const f32x4*)(Kr + (size_t)(e0 + rr) * (2 * C_SZ) + c0 + lq * 4);
      *(f32x4*)(&Tr[rr][lq * 4]) = v;
    }
    __syncthreads();
    // read-transpose: lane reads 8 e's of one column c; bank = (4j + rc) % 32
    // -> 16 distinct banks per quarter-wave, conflict-free
#pragma unroll
    for (int i = 0; i < 2; ++i) {
      const int c = rc + 32 * i;
      short8 pk;
      float sq = 0.f;
#pragma unroll
      for (int j = 0; j < 8; ++j) {
        const float v = Tr[ro * 8 + j][c];
        sq += v * v;
        pk[j] = (short)f32_to_bf16(v);
      }
      accv[i] += sq;
      *(short8*)(Bt + (size_t)(c0 + c) * E_SZ + e0 + ro * 8) = pk;
    }
    __syncthreads();
  }
  part[rc][ro]      = accv[0];
  part[rc + 32][ro] = accv[1];
  __syncthreads();
  if (t < 64) {
    float s = 0.f;
#pragma unroll
    for (int o = 0; o < 8; ++o) s += part[t][o];
    invn[c0 + t] = rsqrtf(s);
  }
}

// ---------------- cos2_tgt[b]: one wave per row ----------------------------
__global__ __launch_bounds__(64) void k_cos2(
    const float* __restrict__ emb, const float* __restrict__ Kr,
    const int* __restrict__ label, float* __restrict__ cos2t) {
  const int b = blockIdx.x;
  const int l = threadIdx.x;
  const int lb = label[b];
  float s1 = 0.f, s2 = 0.f;
#pragma unroll
  for (int e = l; e < E_SZ; e += 64) {
    const float a  = emb[b * E_SZ + e];
    const float kv = Kr[(size_t)e * (2 * C_SZ) + C_SZ + lb];
    s1 += a * kv;
    s2 += kv * kv;
  }
#pragma unroll
  for (int off = 32; off > 0; off >>= 1) {
    s1 += __shfl_down(s1, off);
    s2 += __shfl_down(s2, off);
  }
  if (l == 0) {
    float cv = s1 * rsqrtf(s2);
    cv = fminf(fmaxf(cv, -1.0f + EPSC), 1.0f - EPSC);
    cos2t[b] = cv;
  }
}

// ---------------- main MFMA GEMM + fused epilogue --------------------------
// v2: double-buffered LDS + prefetch-next-K-tile before MFMA (T3-minimum
//     2-phase), bijective XCD-chunked swizzle, nontemporal epilogue stores.
__global__ __launch_bounds__(256) void k_gemm(
    const unsigned short* __restrict__ Abf, const unsigned short* __restrict__ Bt,
    const float* __restrict__ invn, const int* __restrict__ label,
    const float* __restrict__ g_ang, const float* __restrict__ g_add,
    const float* __restrict__ cos2t,
    float* __restrict__ out0, float* __restrict__ out1, float* __restrict__ tgtv1) {
  __shared__ __align__(16) unsigned short As[2][4096];   // 2 x 128x32 bf16
  __shared__ __align__(16) unsigned short Bs[2][4096];
  __shared__ int   lab_s[128];
  __shared__ float ga_s[128];
  __shared__ float gd_s[128];
  __shared__ float c2_s[128];
  __shared__ float inv_s[128];

  const int tid = threadIdx.x;
  // bijective XCD-chunked swizzle (m204): hardware assigns dispatch id d to
  // XCD d%8; give each XCD a contiguous chunk of logical ids so the 4
  // m-blocks sharing one B-panel hit the same L2.
  const int nwg = 4 * NTILES;                 // 2212
  const int q = nwg >> 3, r = nwg & 7;        // 276, 4
  const int xcd = blockIdx.x & 7, pos = blockIdx.x >> 3;
  const int logical = (xcd < r ? xcd * (q + 1) : r * (q + 1) + (xcd - r) * q) + pos;
  const int m0 = (logical & 3) * 128;         // 4 m-tiles consecutive -> same XCD
  const int n0 = (logical >> 2) * 128;

  if (tid < 128) {
    lab_s[tid] = label[m0 + tid];
    ga_s[tid]  = g_ang[m0 + tid];
    gd_s[tid]  = g_add[m0 + tid];
    c2_s[tid]  = cos2t[m0 + tid];
    inv_s[tid] = invn[n0 + tid];
  }

  f32x4 acc[4][4];
#pragma unroll
  for (int i = 0; i < 4; ++i)
#pragma unroll
    for (int j = 0; j < 4; ++j) acc[i][j] = (f32x4){0.f, 0.f, 0.f, 0.f};

  const int l  = tid & 63;
  const int w  = tid >> 6;
  const int wm = (w >> 1) * 64;
  const int wn = (w & 1) * 64;

  const int srow = tid >> 2;
  const int scol = (tid & 3) * 8;
  const unsigned short* Ag0 = Abf + (size_t)(m0 + srow) * E_SZ + scol;
  const unsigned short* Bg0 = Bt  + (size_t)(n0 + srow) * E_SZ + scol;

  const int ldsoff = tid * 16;
  const int lr  = l & 15;
  const int lqb = (l >> 4) * 16;

  // prologue: stage kt=0 into buffer 0
  {
    char* AsB = (char*)As[0]; char* BsB = (char*)Bs[0];
    load16(AsB + ldsoff,        Ag0);
    load16(AsB + 4096 + ldsoff, Ag0 + 64 * E_SZ);
    load16(BsB + ldsoff,        Bg0);
    load16(BsB + 4096 + ldsoff, Bg0 + 64 * E_SZ);
  }
  __syncthreads();   // compiler drains vmcnt(0) here

  int cur = 0;
  for (int kt = 0; kt < 16; ++kt) {
    // issue next-tile stage BEFORE compute: HBM latency hides under MFMA
    if (kt < 15) {
      const int kn = (kt + 1) * 32;
      char* AsB = (char*)As[cur ^ 1]; char* BsB = (char*)Bs[cur ^ 1];
      load16(AsB + ldsoff,        Ag0 + kn);
      load16(AsB + 4096 + ldsoff, Ag0 + 64 * E_SZ + kn);
      load16(BsB + ldsoff,        Bg0 + kn);
      load16(BsB + 4096 + ldsoff, Bg0 + 64 * E_SZ + kn);
    }
    const char* AsB = (const char*)As[cur];
    const char* BsB = (const char*)Bs[cur];
    short8 af[4], bfv[4];
#pragma unroll
    for (int mi = 0; mi < 4; ++mi)
      af[mi] = *(const short8*)(AsB + (wm + mi * 16 + lr) * 64 + lqb);
#pragma unroll
    for (int ni = 0; ni < 4; ++ni)
      bfv[ni] = *(const short8*)(BsB + (wn + ni * 16 + lr) * 64 + lqb);
#pragma unroll
    for (int mi = 0; mi < 4; ++mi)
#pragma unroll
      for (int ni = 0; ni < 4; ++ni)
        acc[mi][ni] = __builtin_amdgcn_mfma_f32_16x16x32_bf16(af[mi], bfv[ni], acc[mi][ni], 0, 0, 0);
    __syncthreads();   // waits prefetch (vmcnt0) + all reads of As[cur] done
    cur ^= 1;
  }

  // epilogue: C/D layout col = lane&15, row = (lane>>4)*4 + reg
  const int lq4 = (l >> 4) * 4;
#pragma unroll
  for (int mi = 0; mi < 4; ++mi) {
    const int blb = wm + mi * 16 + lq4;
#pragma unroll
    for (int ni = 0; ni < 4; ++ni) {
      const int cl = wn + ni * 16 + lr;
      const int c  = n0 + cl;
      if (c < C_SZ) {
        const float inv = inv_s[cl];
        const f32x4 a = acc[mi][ni];
#pragma unroll
        for (int rg = 0; rg < 4; ++rg) {
          const int bl = blb + rg;
          const int b  = m0 + bl;
          float w1 = a[rg] * inv;
          w1 = fminf(fmaxf(w1, -1.0f + EPSC), 1.0f - EPSC);
          float v0 = w1 * SC;   // non-target: cos(acos(w1)) == w1
          float v1 = v0;
          if (c == lab_s[bl]) {                 // rare: one column per row
            const float ga = ga_s[bl];
            const float gd = gd_s[bl];
            float th = acosf(w1) + ga;
            th = fminf(fmaxf(th, EPSC), PI_F - EPSC);
            v0 = (cosf(th) - gd) * SC;
            const float w2 = c2_s[bl];
            float th2 = acosf(w2) + ga;
            th2 = fminf(fmaxf(th2, EPSC), PI_F - EPSC);
            v1 = (cosf(th2) - gd) * SC;
            if (tgtv1) tgtv1[b] = v1;
          }
          const size_t off = (size_t)b * C_SZ + c;
          __builtin_nontemporal_store(v0, out0 + off);
          if (out1) __builtin_nontemporal_store(v1, out1 + off);
        }
      }
    }
  }
}

// ---------------- fallback: out1 = out0 with targets patched ---------------
__global__ __launch_bounds__(256) void k_patch(
    const float* __restrict__ out0, const int* __restrict__ label,
    const float* __restrict__ tgtv1, float* __restrict__ out1) {
  const int b = blockIdx.y;
  const int i2 = (blockIdx.x * 256 + threadIdx.x) * 2;
  if (i2 >= C_SZ) return;
  const size_t off = (size_t)b * C_SZ + i2;
  float2 v = *(const float2*)(out0 + off);
  const int lb = label[b];
  if (lb == i2)          v.x = tgtv1[b];
  else if (lb == i2 + 1) v.y = tgtv1[b];
  *(float2*)(out1 + off) = v;
}

extern "C" void kernel_launch(void* const* d_in, const int* in_sizes, int n_in,
                              void* d_out, int out_size, void* d_ws, size_t ws_size,
                              hipStream_t stream) {
  const float* emb   = (const float*)d_in[0];
  const float* norms = (const float*)d_in[1];
  const int*   label = (const int*)d_in[2];
  const float* Kr    = (const float*)d_in[3];

  float* out  = (float*)d_out;
  float* out0 = out;
  float* out1 = out + (size_t)B_SZ * C_SZ;
  float* outcw = out + (size_t)2 * B_SZ * C_SZ;

  char* ws = (char*)d_ws;
  unsigned short* Abf = (unsigned short*)(ws);          // 524288 B
  float* invn  = (float*)(ws + 524288);                 // NPAD*4 = 283136 B
  float* g_ang = (float*)(ws + 807424);
  float* g_add = (float*)(ws + 809472);
  float* c2    = (float*)(ws + 811520);
  float* tgtv1 = (float*)(ws + 813568);
  const size_t bt_off = 1048576;
  const size_t need_direct = bt_off + (size_t)NPAD * E_SZ * 2;  // 73.5 MB
  const bool direct = ws_size >= need_direct;
  unsigned short* Bt = direct
      ? (unsigned short*)(ws + bt_off)
      : (unsigned short*)((char*)d_out + (size_t)B_SZ * C_SZ * 4);  // out1 region

  k_stats<<<1, 512, 0, stream>>>(norms, label, g_ang, g_add, outcw);
  k_convert_emb<<<(B_SZ * E_SZ) / (256 * 8), 256, 0, stream>>>(emb, Abf);
  k_prep_b<<<NPAD / 64, 256, 0, stream>>>(Kr, Bt, invn);
  k_cos2<<<B_SZ, 64, 0, stream>>>(emb, Kr, label, c2);
  k_gemm<<<dim3(4 * NTILES), 256, 0, stream>>>(Abf, Bt, invn, label, g_ang, g_add, c2,
                                               out0, direct ? out1 : (float*)nullptr,
                                               direct ? (float*)nullptr : tgtv1);
  if (!direct) {
    k_patch<<<dim3((C_SZ / 2 + 255) / 256, B_SZ), 256, 0, stream>>>(out0, label, tgtv1, out1);
  }
}

// Round 2
// 590.236 us; speedup vs baseline: 1.3357x; 1.3357x over previous
//
#include <hip/hip_runtime.h>

#define B_SZ 512
#define E_SZ 512
#define C_SZ 70722
#define NPAD 70784   /* 553*128 */
#define NTILES 553
#define EPSC 0.001f
#define MMARG 0.4f
#define HC 0.333f
#define SC 64.0f
#define PI_F 3.14159265358979323846f

typedef __attribute__((ext_vector_type(8))) short short8;
typedef __attribute__((ext_vector_type(4))) float f32x4;

__device__ __forceinline__ unsigned short f32_to_bf16(float f) {
  unsigned int u = __builtin_bit_cast(unsigned int, f);
  u += 0x7fffu + ((u >> 16) & 1u);   // RNE (inputs finite)
  return (unsigned short)(u >> 16);
}

__device__ __forceinline__ void load16(void* lds, const void* g) {
  __builtin_amdgcn_global_load_lds(
      (const __attribute__((address_space(1))) void*)g,
      (__attribute__((address_space(3))) void*)lds, 16, 0, 0);
}

// ---------------- stats: per-row scalars (1 block, 512 threads) -------------
__global__ __launch_bounds__(512) void k_stats(
    const float* __restrict__ norms, const int* __restrict__ label,
    float* __restrict__ g_ang, float* __restrict__ g_add,
    float* __restrict__ out_cw) {
  __shared__ float sn[512];
  __shared__ int   lab[512];
  __shared__ float red[512];
  const int t = threadIdx.x;
  float x = norms[t];
  x = fminf(fmaxf(x, 0.001f), 100.0f);   // safe_norms
  sn[t] = x; lab[t] = label[t]; red[t] = x;
  __syncthreads();
  for (int s = 256; s > 0; s >>= 1) { if (t < s) red[t] += red[t + s]; __syncthreads(); }
  const float mean = red[0] * (1.0f / 512.0f);
  __syncthreads();
  const float d = x - mean;
  red[t] = d * d;
  __syncthreads();
  for (int s = 256; s > 0; s >>= 1) { if (t < s) red[t] += red[t + s]; __syncthreads(); }
  const float stdv = sqrtf(red[0] / 511.0f);     // ddof=1; T_ALPHA=1
  const float denom = stdv + EPSC;
  float cnt = 0.f, sum = 0.f;
  const int myl = lab[t];
  for (int j = 0; j < 512; ++j) { if (lab[j] == myl) { cnt += 1.0f; sum += sn[j]; } }
  const float cwm = sum / cnt;
  const float ms = fminf(fmaxf((x - mean) / denom * HC, -1.0f), 1.0f);
  out_cw[t] = fminf(fmaxf((x - cwm) / denom, -1.0f), 1.0f) * HC;
  g_ang[t] = -MMARG * ms;
  g_add[t] = MMARG + MMARG * ms;
}

// ---------------- emb f32 -> bf16 (vectorized: 8 elems/thread) --------------
__global__ __launch_bounds__(256) void k_convert_emb(
    const float* __restrict__ emb, unsigned short* __restrict__ Abf) {
  const int i = (blockIdx.x * 256 + threadIdx.x) * 8;
  const f32x4 a = *(const f32x4*)(emb + i);
  const f32x4 b = *(const f32x4*)(emb + i + 4);
  short8 o;
  o[0] = (short)f32_to_bf16(a[0]); o[1] = (short)f32_to_bf16(a[1]);
  o[2] = (short)f32_to_bf16(a[2]); o[3] = (short)f32_to_bf16(a[3]);
  o[4] = (short)f32_to_bf16(b[0]); o[5] = (short)f32_to_bf16(b[1]);
  o[6] = (short)f32_to_bf16(b[2]); o[7] = (short)f32_to_bf16(b[3]);
  *(short8*)(Abf + i) = o;
}

// ------- transpose+convert kernel[:,0,:] -> Bt[c][e] bf16, + invnorm --------
__global__ __launch_bounds__(256) void k_prep_b(
    const float* __restrict__ Kr, unsigned short* __restrict__ Bt,
    float* __restrict__ invn) {
  __shared__ __align__(16) float Tr[64][68];   // [e][c], stride 68 keeps 16B-aligned vec writes
  __shared__ float part[64][8];
  const int t  = threadIdx.x;
  const int c0 = blockIdx.x * 64;
  const int lr = t >> 4;        // load phase: e-row base 0..15
  const int lq = t & 15;        // load phase: float4 column index
  const int rc = t & 31;        // read phase: c base (c = rc, rc+32)
  const int ro = t >> 5;        // read phase: e-octet 0..7
  float accv[2] = {0.f, 0.f};

  for (int et = 0; et < 8; ++et) {
    const int e0 = et * 64;
#pragma unroll
    for (int i = 0; i < 4; ++i) {
      const int rr = lr + 16 * i;
      const f32x4 v = *(const f32x4*)(Kr + (size_t)(e0 + rr) * (2 * C_SZ) + c0 + lq * 4);
      *(f32x4*)(&Tr[rr][lq * 4]) = v;
    }
    __syncthreads();
#pragma unroll
    for (int i = 0; i < 2; ++i) {
      const int c = rc + 32 * i;
      short8 pk;
      float sq = 0.f;
#pragma unroll
      for (int j = 0; j < 8; ++j) {
        const float v = Tr[ro * 8 + j][c];
        sq += v * v;
        pk[j] = (short)f32_to_bf16(v);
      }
      accv[i] += sq;
      *(short8*)(Bt + (size_t)(c0 + c) * E_SZ + e0 + ro * 8) = pk;
    }
    __syncthreads();
  }
  part[rc][ro]      = accv[0];
  part[rc + 32][ro] = accv[1];
  __syncthreads();
  if (t < 64) {
    float s = 0.f;
#pragma unroll
    for (int o = 0; o < 8; ++o) s += part[t][o];
    invn[c0 + t] = rsqrtf(s);
  }
}

// ---------------- cos2_tgt[b]: one wave per row ----------------------------
__global__ __launch_bounds__(64) void k_cos2(
    const float* __restrict__ emb, const float* __restrict__ Kr,
    const int* __restrict__ label, float* __restrict__ cos2t) {
  const int b = blockIdx.x;
  const int l = threadIdx.x;
  const int lb = label[b];
  float s1 = 0.f, s2 = 0.f;
#pragma unroll
  for (int e = l; e < E_SZ; e += 64) {
    const float a  = emb[b * E_SZ + e];
    const float kv = Kr[(size_t)e * (2 * C_SZ) + C_SZ + lb];
    s1 += a * kv;
    s2 += kv * kv;
  }
#pragma unroll
  for (int off = 32; off > 0; off >>= 1) {
    s1 += __shfl_down(s1, off);
    s2 += __shfl_down(s2, off);
  }
  if (l == 0) {
    float cv = s1 * rsqrtf(s2);
    cv = fminf(fmaxf(cv, -1.0f + EPSC), 1.0f - EPSC);
    cos2t[b] = cv;
  }
}

// ---------------- main MFMA GEMM + fused epilogue --------------------------
// v3: 512 threads (8 waves of 64x32) -> 24 waves/CU at same 35KB LDS;
//     double-buffered prefetch kept; XOR k-chunk swizzle (linear LDS dest +
//     inverse-permuted global source + same permutation on read) makes
//     fragment ds_read_b128 2-way (free); plain stores (no NT).
__global__ __launch_bounds__(512) void k_gemm(
    const unsigned short* __restrict__ Abf, const unsigned short* __restrict__ Bt,
    const float* __restrict__ invn, const int* __restrict__ label,
    const float* __restrict__ g_ang, const float* __restrict__ g_add,
    const float* __restrict__ cos2t,
    float* __restrict__ out0, float* __restrict__ out1, float* __restrict__ tgtv1) {
  __shared__ __align__(16) unsigned short As[2][4096];   // 2 x (128 rows x 32 bf16)
  __shared__ __align__(16) unsigned short Bs[2][4096];
  __shared__ int   lab_s[128];
  __shared__ float ga_s[128];
  __shared__ float gd_s[128];
  __shared__ float c2_s[128];
  __shared__ float inv_s[128];

  const int tid = threadIdx.x;
  // bijective XCD-chunked swizzle (m204)
  const int nwg = 4 * NTILES;                 // 2212
  const int q = nwg >> 3, r = nwg & 7;        // 276, 4
  const int xcd = blockIdx.x & 7, pos = blockIdx.x >> 3;
  const int logical = (xcd < r ? xcd * (q + 1) : r * (q + 1) + (xcd - r) * q) + pos;
  const int m0 = (logical & 3) * 128;         // 4 m-tiles consecutive -> same XCD L2
  const int n0 = (logical >> 2) * 128;

  if (tid < 128) {
    lab_s[tid] = label[m0 + tid];
    ga_s[tid]  = g_ang[m0 + tid];
    gd_s[tid]  = g_add[m0 + tid];
    c2_s[tid]  = cos2t[m0 + tid];
    inv_s[tid] = invn[n0 + tid];
  }

  f32x4 acc[4][2];
#pragma unroll
  for (int i = 0; i < 4; ++i)
#pragma unroll
    for (int j = 0; j < 2; ++j) acc[i][j] = (f32x4){0.f, 0.f, 0.f, 0.f};

  const int l  = tid & 63;
  const int w  = tid >> 6;          // 0..7
  const int wm = (w >> 2) * 64;     // 2 m-halves
  const int wn = (w & 3) * 32;      // 4 n-quarters

  // staging: thread t owns LDS slot t (16B). slot t = row t>>2, chunk-pos t&3.
  // source chunk is XOR-permuted so that read-side swizzle is the inverse.
  const int srow = tid >> 2;
  const int skey = (srow >> 1) & 3;
  const int schunk = (tid & 3) ^ skey;
  const unsigned short* Ag0 = Abf + (size_t)(m0 + srow) * E_SZ + schunk * 8;
  const unsigned short* Bg0 = Bt  + (size_t)(n0 + srow) * E_SZ + schunk * 8;
  const int ldsoff = tid * 16;

  // fragment read: row = base+lr, k-chunk kq swizzled by ((row>>1)&3) == ((lr>>1)&3)
  const int lr  = l & 15;
  const int kq  = l >> 4;                       // 0..3
  const int kxa = (kq ^ ((lr >> 1) & 3)) * 16;  // swizzled byte offset in 64B row

  // prologue: stage kt=0 into buffer 0
  load16((char*)As[0] + ldsoff, Ag0);
  load16((char*)Bs[0] + ldsoff, Bg0);
  __syncthreads();   // drains vmcnt(0)

  int cur = 0;
  for (int kt = 0; kt < 16; ++kt) {
    if (kt < 15) {   // prefetch next K-tile before compute
      const int kn = (kt + 1) * 32;
      load16((char*)As[cur ^ 1] + ldsoff, Ag0 + kn);
      load16((char*)Bs[cur ^ 1] + ldsoff, Bg0 + kn);
    }
    const char* AsB = (const char*)As[cur];
    const char* BsB = (const char*)Bs[cur];
    short8 af[4], bfv[2];
#pragma unroll
    for (int mi = 0; mi < 4; ++mi)
      af[mi] = *(const short8*)(AsB + (wm + mi * 16 + lr) * 64 + kxa);
#pragma unroll
    for (int ni = 0; ni < 2; ++ni)
      bfv[ni] = *(const short8*)(BsB + (wn + ni * 16 + lr) * 64 + kxa);
#pragma unroll
    for (int mi = 0; mi < 4; ++mi)
#pragma unroll
      for (int ni = 0; ni < 2; ++ni)
        acc[mi][ni] = __builtin_amdgcn_mfma_f32_16x16x32_bf16(af[mi], bfv[ni], acc[mi][ni], 0, 0, 0);
    __syncthreads();   // prefetch landed + all reads of As[cur] done
    cur ^= 1;
  }

  // epilogue: C/D layout col = lane&15, row = (lane>>4)*4 + reg
  const int lq4 = (l >> 4) * 4;
#pragma unroll
  for (int mi = 0; mi < 4; ++mi) {
    const int blb = wm + mi * 16 + lq4;
#pragma unroll
    for (int ni = 0; ni < 2; ++ni) {
      const int cl = wn + ni * 16 + lr;
      const int c  = n0 + cl;
      if (c < C_SZ) {
        const float inv = inv_s[cl];
        const f32x4 a = acc[mi][ni];
#pragma unroll
        for (int rg = 0; rg < 4; ++rg) {
          const int bl = blb + rg;
          const int b  = m0 + bl;
          float w1 = a[rg] * inv;
          w1 = fminf(fmaxf(w1, -1.0f + EPSC), 1.0f - EPSC);
          float v0 = w1 * SC;   // non-target: cos(acos(w1)) == w1
          float v1 = v0;
          if (c == lab_s[bl]) {                 // rare: one column per row
            const float ga = ga_s[bl];
            const float gd = gd_s[bl];
            float th = acosf(w1) + ga;
            th = fminf(fmaxf(th, EPSC), PI_F - EPSC);
            v0 = (cosf(th) - gd) * SC;
            const float w2 = c2_s[bl];
            float th2 = acosf(w2) + ga;
            th2 = fminf(fmaxf(th2, EPSC), PI_F - EPSC);
            v1 = (cosf(th2) - gd) * SC;
            if (tgtv1) tgtv1[b] = v1;
          }
          const size_t off = (size_t)b * C_SZ + c;
          out0[off] = v0;
          if (out1) out1[off] = v1;
        }
      }
    }
  }
}

// ---------------- fallback: out1 = out0 with targets patched ---------------
__global__ __launch_bounds__(256) void k_patch(
    const float* __restrict__ out0, const int* __restrict__ label,
    const float* __restrict__ tgtv1, float* __restrict__ out1) {
  const int b = blockIdx.y;
  const int i2 = (blockIdx.x * 256 + threadIdx.x) * 2;
  if (i2 >= C_SZ) return;
  const size_t off = (size_t)b * C_SZ + i2;
  float2 v = *(const float2*)(out0 + off);
  const int lb = label[b];
  if (lb == i2)          v.x = tgtv1[b];
  else if (lb == i2 + 1) v.y = tgtv1[b];
  *(float2*)(out1 + off) = v;
}

extern "C" void kernel_launch(void* const* d_in, const int* in_sizes, int n_in,
                              void* d_out, int out_size, void* d_ws, size_t ws_size,
                              hipStream_t stream) {
  const float* emb   = (const float*)d_in[0];
  const float* norms = (const float*)d_in[1];
  const int*   label = (const int*)d_in[2];
  const float* Kr    = (const float*)d_in[3];

  float* out  = (float*)d_out;
  float* out0 = out;
  float* out1 = out + (size_t)B_SZ * C_SZ;
  float* outcw = out + (size_t)2 * B_SZ * C_SZ;

  char* ws = (char*)d_ws;
  unsigned short* Abf = (unsigned short*)(ws);          // 524288 B
  float* invn  = (float*)(ws + 524288);                 // NPAD*4 = 283136 B
  float* g_ang = (float*)(ws + 807424);
  float* g_add = (float*)(ws + 809472);
  float* c2    = (float*)(ws + 811520);
  float* tgtv1 = (float*)(ws + 813568);
  const size_t bt_off = 1048576;
  const size_t need_direct = bt_off + (size_t)NPAD * E_SZ * 2;  // 73.5 MB
  const bool direct = ws_size >= need_direct;
  unsigned short* Bt = direct
      ? (unsigned short*)(ws + bt_off)
      : (unsigned short*)((char*)d_out + (size_t)B_SZ * C_SZ * 4);  // out1 region

  k_stats<<<1, 512, 0, stream>>>(norms, label, g_ang, g_add, outcw);
  k_convert_emb<<<(B_SZ * E_SZ) / (256 * 8), 256, 0, stream>>>(emb, Abf);
  k_prep_b<<<NPAD / 64, 256, 0, stream>>>(Kr, Bt, invn);
  k_cos2<<<B_SZ, 64, 0, stream>>>(emb, Kr, label, c2);
  k_gemm<<<dim3(4 * NTILES), 512, 0, stream>>>(Abf, Bt, invn, label, g_ang, g_add, c2,
                                               out0, direct ? out1 : (float*)nullptr,
                                               direct ? (float*)nullptr : tgtv1);
  if (!direct) {
    k_patch<<<dim3((C_SZ / 2 + 255) / 256, B_SZ), 256, 0, stream>>>(out0, label, tgtv1, out1);
  }
}